// Round 11
// baseline (1607.971 us; speedup 1.0000x reference)
//
#include <hip/hip_runtime.h>

// ---------------------------------------------------------------------------
// FullModelSnowflake.  R10: attention two-round wave-merge — reuse one
// [64][129] LDS buffer for a0 then a1, halving LDS 70->37KB so 3 blocks/CU
// fit (24 waves/CU vs 16); conflict-free reduce indexing.
// ---------------------------------------------------------------------------

#define B_ 2
#define N_ 1024
#define D_ 128
#define H_ 8
#define DK_ 16
#define L_ 4
#define KG_ 16
#define KLOC_ 8
#define COARSE_ 512
#define NCH_ 16          // candidate chunks (64 candidates each)
#define AW_ 8            // waves per attention block
#define KSP_ 4           // block-level key splits
#define PREC_ 17         // floats per attention partial (sum + 16 acc)
#define MQ_ 16           // queries per merge block

static __device__ __forceinline__ float wave_sum(float v) {
    #pragma unroll
    for (int off = 32; off > 0; off >>= 1) v += __shfl_xor(v, off);
    return v;
}
static __device__ __forceinline__ float half_sum(float v) {
    #pragma unroll
    for (int off = 16; off > 0; off >>= 1) v += __shfl_xor(v, off);
    return v;
}

// ---------------- LDS-staged GEMM body: returns this thread's acc ----------
template <int CIN, bool RELU, bool BIAS_HALF>
static __device__ __forceinline__ float4 gemm_body(
        const float* __restrict__ X, const float* __restrict__ W,
        const float* __restrict__ bias, int wstride, int col0) {
    __shared__ float Xs[8 * CIN];
    __shared__ float Ws[64][128];
    int tid = threadIdx.x;
    int row0 = blockIdx.x * 8;
    constexpr int NX4 = 2 * CIN;
    {
        const float4* xg = (const float4*)(X + (size_t)row0 * CIN);
        float4* xs4 = (float4*)Xs;
        #pragma unroll
        for (int i = 0; i < (NX4 + 255) / 256; ++i) {
            int t = tid + i * 256;
            if ((NX4 % 256 == 0) || t < NX4) xs4[t] = xg[t];
        }
    }
    int col4 = (tid & 31) << 2;
    int rowl = tid >> 5;
    float4 acc;
    if (BIAS_HALF) {
        acc.x = bias[(col0 + col4) >> 1];
        acc.y = bias[(col0 + col4 + 1) >> 1];
        acc.z = bias[(col0 + col4 + 2) >> 1];
        acc.w = bias[(col0 + col4 + 3) >> 1];
    } else {
        acc = *(const float4*)(bias + col0 + col4);
    }
    for (int c0 = 0; c0 < CIN; c0 += 64) {
        __syncthreads();
        #pragma unroll
        for (int i = 0; i < 8; ++i) {
            int flat = tid + i * 256;
            int wr = flat >> 5, wc = (flat & 31) << 2;
            *(float4*)&Ws[wr][wc] =
                *(const float4*)(W + (size_t)(c0 + wr) * wstride + col0 + wc);
        }
        __syncthreads();
        const float* xrow = Xs + rowl * CIN + c0;
        #pragma unroll
        for (int c = 0; c < 64; ++c) {
            float xv = xrow[c];
            float4 w = *(const float4*)&Ws[c][col4];
            acc.x += xv * w.x; acc.y += xv * w.y;
            acc.z += xv * w.z; acc.w += xv * w.w;
        }
    }
    if (RELU) {
        acc.x = fmaxf(acc.x, 0.f); acc.y = fmaxf(acc.y, 0.f);
        acc.z = fmaxf(acc.z, 0.f); acc.w = fmaxf(acc.w, 0.f);
    }
    return acc;
}

template <int CIN, bool RELU, bool BIAS_HALF>
__global__ __launch_bounds__(256) void gemm128_kernel(
        const float* __restrict__ X, const float* __restrict__ W,
        const float* __restrict__ bias, float* __restrict__ Y,
        int wstride, int ystride) {
    int col0 = blockIdx.y * 128;
    float4 acc = gemm_body<CIN, RELU, BIAS_HALF>(X, W, bias, wstride, col0);
    int col4 = (threadIdx.x & 31) << 2;
    int row = blockIdx.x * 8 + (threadIdx.x >> 5);
    *(float4*)(Y + (size_t)row * ystride + col0 + col4) = acc;
}

// GEMM (Cout=128) fused with residual-add + LayerNorm epilogue.
template <int CIN>
__global__ __launch_bounds__(256) void gemm_ln_kernel(
        const float* __restrict__ X, const float* __restrict__ W,
        const float* __restrict__ bias, const float* __restrict__ res,
        const float* __restrict__ g, const float* __restrict__ bt,
        float* __restrict__ Y) {
    float4 acc = gemm_body<CIN, false, false>(X, W, bias, 128, 0);
    int col4 = (threadIdx.x & 31) << 2;
    int row = blockIdx.x * 8 + (threadIdx.x >> 5);
    float4 r = *(const float4*)(res + (size_t)row * D_ + col4);
    acc.x += r.x; acc.y += r.y; acc.z += r.z; acc.w += r.w;
    float mean = half_sum(acc.x + acc.y + acc.z + acc.w) * (1.0f / D_);
    float dx = acc.x - mean, dy = acc.y - mean, dz = acc.z - mean, dw = acc.w - mean;
    float var = half_sum(dx * dx + dy * dy + dz * dz + dw * dw) * (1.0f / D_);
    float rstd = rsqrtf(var + 1e-5f);
    float4 gv = *(const float4*)(g + col4);
    float4 bv = *(const float4*)(bt + col4);
    float4 o;
    o.x = dx * rstd * gv.x + bv.x;
    o.y = dy * rstd * gv.y + bv.y;
    o.z = dz * rstd * gv.z + bv.z;
    o.w = dw * rstd * gv.w + bv.w;
    *(float4*)(Y + (size_t)row * D_ + col4) = o;
}

// fused QKV: 3 W-panels via blockIdx.y
__global__ __launch_bounds__(256) void qkv3_kernel(
        const float* __restrict__ X,
        const float* __restrict__ Wq, const float* __restrict__ bq,
        const float* __restrict__ Wk, const float* __restrict__ bk,
        const float* __restrict__ Wv, const float* __restrict__ bv,
        float* __restrict__ Q, float* __restrict__ K, float* __restrict__ V) {
    const float* W; const float* bias; float* Y;
    if (blockIdx.y == 0)      { W = Wq; bias = bq; Y = Q; }
    else if (blockIdx.y == 1) { W = Wk; bias = bk; Y = K; }
    else                      { W = Wv; bias = bv; Y = V; }
    float4 acc = gemm_body<128, false, false>(X, W, bias, 128, 0);
    int col4 = (threadIdx.x & 31) << 2;
    int row = blockIdx.x * 8 + (threadIdx.x >> 5);
    *(float4*)(Y + (size_t)row * 128 + col4) = acc;
}

// ---------------- KNN pass 1: per-chunk partial top-16 ---------------------
__global__ void knn_part_kernel(const float* __restrict__ coords,
                                float* __restrict__ pd, int* __restrict__ pi) {
    int blk = blockIdx.x;
    int qb = blk & 15;
    int ch = (blk >> 4) & 15;
    int b = blk >> 8;
    int lane = threadIdx.x;
    int q = qb * 64 + lane;
    __shared__ float4 sc[64];
    const float* cb = coords + (size_t)b * N_ * 3;
    {
        int m = ch * 64 + lane;
        float x = cb[m * 3], y = cb[m * 3 + 1], z = cb[m * 3 + 2];
        sc[lane] = make_float4(x, y, z, x * x + y * y + z * z);
    }
    __syncthreads();
    float qx = cb[q * 3], qy = cb[q * 3 + 1], qz = cb[q * 3 + 2];
    float q2 = qx * qx + qy * qy + qz * qz;
    float bd[KG_]; int bi[KG_];
    #pragma unroll
    for (int j = 0; j < KG_; ++j) { bd[j] = 3e38f; bi[j] = 0; }
    for (int j = 0; j < 64; ++j) {
        int m = ch * 64 + j;
        float4 c = sc[j];
        float dot = qx * c.x + qy * c.y + qz * c.z;
        float d = (q2 - 2.0f * dot) + c.w;
        d = (m == q) ? 3e38f : d;
        if (d < bd[KG_ - 1]) {
            #pragma unroll
            for (int jj = KG_ - 1; jj > 0; --jj) {
                bool shf = d < bd[jj - 1];
                bool plc = !shf && (d < bd[jj]);
                bd[jj] = shf ? bd[jj - 1] : (plc ? d : bd[jj]);
                bi[jj] = shf ? bi[jj - 1] : (plc ? m : bi[jj]);
            }
            if (d < bd[0]) { bd[0] = d; bi[0] = m; }
        }
    }
    size_t base = (((size_t)b * N_ + q) * NCH_ + ch) * KG_;
    #pragma unroll
    for (int j = 0; j < KG_; ++j) { pd[base + j] = bd[j]; pi[base + j] = bi[j]; }
}

// ---------------- KNN pass 2: LDS-staged merge of 16 sorted lists ----------
__global__ __launch_bounds__(256) void knn_merge_kernel(
        const float* __restrict__ pd, const int* __restrict__ pi,
        int* __restrict__ knn) {
    __shared__ float sd[MQ_][NCH_ * KG_ + 1];
    __shared__ int   si[MQ_][NCH_ * KG_ + 1];
    size_t qg0 = (size_t)blockIdx.x * MQ_;
    size_t base = qg0 * NCH_ * KG_;
    for (int i = threadIdx.x; i < MQ_ * NCH_ * KG_; i += 256) {
        int r = i >> 8, cix = i & 255;
        sd[r][cix] = pd[base + i];
        si[r][cix] = pi[base + i];
    }
    __syncthreads();
    int t = threadIdx.x;
    if (t < MQ_) {
        const float* cd0 = sd[t];
        const int* ci0 = si[t];
        float bd[KG_]; int bi[KG_];
        #pragma unroll
        for (int j = 0; j < KG_; ++j) { bd[j] = 3e38f; bi[j] = 0; }
        for (int ch = 0; ch < NCH_; ++ch) {
            for (int e = 0; e < KG_; ++e) {
                float d = cd0[ch * KG_ + e];
                if (d >= bd[KG_ - 1]) break;
                int m = ci0[ch * KG_ + e];
                #pragma unroll
                for (int jj = KG_ - 1; jj > 0; --jj) {
                    bool shf = d < bd[jj - 1];
                    bool plc = !shf && (d < bd[jj]);
                    bd[jj] = shf ? bd[jj - 1] : (plc ? d : bd[jj]);
                    bi[jj] = shf ? bi[jj - 1] : (plc ? m : bi[jj]);
                }
                if (d < bd[0]) { bd[0] = d; bi[0] = m; }
            }
        }
        int* o = knn + (qg0 + t) * KG_;
        #pragma unroll
        for (int j = 0; j < KG_; ++j) o[j] = bi[j];
    }
}

// ---------------- local KNN pass 1 (k=8) -----------------------------------
__global__ void loc_part_kernel(const float* __restrict__ part,
                                const float* __restrict__ pred,
                                float* __restrict__ pd, int* __restrict__ pi,
                                int Nq) {
    int qb = blockIdx.x, ch = blockIdx.y, b = blockIdx.z;
    int lane = threadIdx.x;
    int q = qb * 64 + lane;
    __shared__ float4 sc[64];
    const float* pb = part + (size_t)b * N_ * 3;
    {
        int m = ch * 64 + lane;
        float x = pb[m * 3], y = pb[m * 3 + 1], z = pb[m * 3 + 2];
        sc[lane] = make_float4(x, y, z, x * x + y * y + z * z);
    }
    __syncthreads();
    const float* pr = pred + ((size_t)b * Nq + q) * 3;
    float qx = pr[0], qy = pr[1], qz = pr[2];
    float q2 = qx * qx + qy * qy + qz * qz;
    float bd[KLOC_]; int bi[KLOC_];
    #pragma unroll
    for (int j = 0; j < KLOC_; ++j) { bd[j] = 3e38f; bi[j] = 0; }
    for (int j = 0; j < 64; ++j) {
        float4 c = sc[j];
        float dot = qx * c.x + qy * c.y + qz * c.z;
        float d = (q2 - 2.0f * dot) + c.w;
        if (d < bd[KLOC_ - 1]) {
            int m = ch * 64 + j;
            #pragma unroll
            for (int jj = KLOC_ - 1; jj > 0; --jj) {
                bool shf = d < bd[jj - 1];
                bool plc = !shf && (d < bd[jj]);
                bd[jj] = shf ? bd[jj - 1] : (plc ? d : bd[jj]);
                bi[jj] = shf ? bi[jj - 1] : (plc ? m : bi[jj]);
            }
            if (d < bd[0]) { bd[0] = d; bi[0] = m; }
        }
    }
    size_t base = (((size_t)b * Nq + q) * NCH_ + ch) * KLOC_;
    #pragma unroll
    for (int j = 0; j < KLOC_; ++j) { pd[base + j] = bd[j]; pi[base + j] = bi[j]; }
}

// ---------------- local KNN pass 2: LDS-staged merge + mean + comb ---------
__global__ __launch_bounds__(256) void loc_merge_kernel(
        const float* __restrict__ part, const float* __restrict__ pred,
        const float* __restrict__ pd, const int* __restrict__ pi,
        float* __restrict__ comb, int Nq) {
    __shared__ float sd[MQ_][NCH_ * KLOC_ + 1];
    __shared__ int   si[MQ_][NCH_ * KLOC_ + 1];
    size_t qg0 = (size_t)blockIdx.x * MQ_;
    size_t base = qg0 * NCH_ * KLOC_;
    for (int i = threadIdx.x; i < MQ_ * NCH_ * KLOC_; i += 256) {
        int r = i >> 7, cix = i & 127;
        sd[r][cix] = pd[base + i];
        si[r][cix] = pi[base + i];
    }
    __syncthreads();
    int t = threadIdx.x;
    if (t < MQ_) {
        const float* cd0 = sd[t];
        const int* ci0 = si[t];
        float bd[KLOC_]; int bi[KLOC_];
        #pragma unroll
        for (int j = 0; j < KLOC_; ++j) { bd[j] = 3e38f; bi[j] = 0; }
        for (int ch = 0; ch < NCH_; ++ch) {
            for (int e = 0; e < KLOC_; ++e) {
                float d = cd0[ch * KLOC_ + e];
                if (d >= bd[KLOC_ - 1]) break;
                int m = ci0[ch * KLOC_ + e];
                #pragma unroll
                for (int jj = KLOC_ - 1; jj > 0; --jj) {
                    bool shf = d < bd[jj - 1];
                    bool plc = !shf && (d < bd[jj]);
                    bd[jj] = shf ? bd[jj - 1] : (plc ? d : bd[jj]);
                    bi[jj] = shf ? bi[jj - 1] : (plc ? m : bi[jj]);
                }
                if (d < bd[0]) { bd[0] = d; bi[0] = m; }
            }
        }
        size_t qg = qg0 + t;
        int b = (int)(qg / Nq);
        const float* pb = part + (size_t)b * N_ * 3;
        float sx = 0.f, sy = 0.f, sz = 0.f;
        #pragma unroll
        for (int j = 0; j < KLOC_; ++j) {
            int m = bi[j];
            sx += pb[m * 3]; sy += pb[m * 3 + 1]; sz += pb[m * 3 + 2];
        }
        const float* pr = pred + qg * 3;
        float* o = comb + qg * 6;
        o[0] = pr[0]; o[1] = pr[1]; o[2] = pr[2];
        o[3] = sx * (1.0f / KLOC_); o[4] = sy * (1.0f / KLOC_); o[5] = sz * (1.0f / KLOC_);
    }
}

// ---------------- GCN aggregation: (x + sum_nb) / (k+1) --------------------
__global__ void gcn_agg_kernel(const float* __restrict__ x,
                               const int* __restrict__ knn,
                               float* __restrict__ agg, int C) {
    int i = blockIdx.x * blockDim.x + threadIdx.x;
    if (i >= B_ * N_ * C) return;
    int c = i % C;
    int n = (i / C) % N_;
    int b = i / (C * N_);
    const int* id = knn + ((size_t)b * N_ + n) * KG_;
    float s = x[((size_t)b * N_ + n) * C + c];
    #pragma unroll
    for (int j = 0; j < KG_; ++j) s += x[((size_t)b * N_ + id[j]) * C + c];
    agg[i] = s * (1.0f / (KG_ + 1));
}

// ---------------- linear: 4 outputs per thread (small cases) ---------------
template <bool RELU>
__global__ void linear4_kernel(const float* __restrict__ X,
                               const float* __restrict__ W,
                               const float* __restrict__ bias,
                               float* __restrict__ Y,
                               int rows, int Cin, int Cout) {
    int co4 = Cout >> 2;
    int idx = blockIdx.x * blockDim.x + threadIdx.x;
    if (idx >= rows * co4) return;
    int r = idx / co4, o4 = (idx - r * co4) << 2;
    const float* x = X + (size_t)r * Cin;
    float4 acc = *(const float4*)(bias + o4);
    #pragma unroll 4
    for (int c = 0; c < Cin; ++c) {
        float xv = x[c];
        float4 w = *(const float4*)(W + (size_t)c * Cout + o4);
        acc.x += xv * w.x; acc.y += xv * w.y; acc.z += xv * w.z; acc.w += xv * w.w;
    }
    if (RELU) {
        acc.x = fmaxf(acc.x, 0.f); acc.y = fmaxf(acc.y, 0.f);
        acc.z = fmaxf(acc.z, 0.f); acc.w = fmaxf(acc.w, 0.f);
    }
    *(float4*)(Y + (size_t)r * Cout + o4) = acc;
}

// ---------------- attention: no-max softmax, two-round LDS merge -----------
__global__ __launch_bounds__(512, 7) void attn_part(
        const float* __restrict__ q,
        const float* __restrict__ k,
        const float* __restrict__ v,
        const float* __restrict__ coords,
        const float* __restrict__ alphap, int layer,
        float* __restrict__ pp) {
    int bh = blockIdx.x & 15;          // b*8 + h
    int t = blockIdx.x >> 4;           // nb*KSP + ks
    int ks = t & (KSP_ - 1);
    int nb = t >> 2;
    int h = bh & 7;
    int b = bh >> 3;
    int wid = threadIdx.x >> 6;
    int lane = threadIdx.x & 63;
    int n0 = nb * 128 + lane;          // second query: n0 + 64
    float alpha = alphap[layer];
    const float* qp0 = q + ((size_t)(b * N_ + n0) * D_ + h * DK_);
    const float* qp1 = qp0 + (size_t)64 * D_;
    float qv0[DK_], qv1[DK_];
    #pragma unroll
    for (int d = 0; d < DK_; ++d) { qv0[d] = qp0[d]; qv1[d] = qp1[d]; }
    const float* cb = coords + (size_t)b * N_ * 3;
    float c0x = cb[n0 * 3], c0y = cb[n0 * 3 + 1], c0z = cb[n0 * 3 + 2];
    float c1x = cb[(n0 + 64) * 3], c1y = cb[(n0 + 64) * 3 + 1], c1z = cb[(n0 + 64) * 3 + 2];
    const float* kb = k + (size_t)b * N_ * D_ + h * DK_;
    const float* vb = v + (size_t)b * N_ * D_ + h * DK_;
    float sm0 = 0.f, sm1 = 0.f;
    float a0[DK_], a1[DK_];
    #pragma unroll
    for (int d = 0; d < DK_; ++d) { a0[d] = 0.f; a1[d] = 0.f; }
    int kbase = ks * 256 + wid * 32;
    #pragma unroll 4
    for (int j = 0; j < 32; ++j) {
        int m = kbase + j;
        const float4* kr = (const float4*)(kb + (size_t)m * D_);
        float4 k0 = kr[0], k1 = kr[1], k2 = kr[2], k3 = kr[3];
        float d0 = qv0[0] * k0.x + qv0[1] * k0.y + qv0[2] * k0.z + qv0[3] * k0.w
                 + qv0[4] * k1.x + qv0[5] * k1.y + qv0[6] * k1.z + qv0[7] * k1.w
                 + qv0[8] * k2.x + qv0[9] * k2.y + qv0[10] * k2.z + qv0[11] * k2.w
                 + qv0[12] * k3.x + qv0[13] * k3.y + qv0[14] * k3.z + qv0[15] * k3.w;
        float d1 = qv1[0] * k0.x + qv1[1] * k0.y + qv1[2] * k0.z + qv1[3] * k0.w
                 + qv1[4] * k1.x + qv1[5] * k1.y + qv1[6] * k1.z + qv1[7] * k1.w
                 + qv1[8] * k2.x + qv1[9] * k2.y + qv1[10] * k2.z + qv1[11] * k2.w
                 + qv1[12] * k3.x + qv1[13] * k3.y + qv1[14] * k3.z + qv1[15] * k3.w;
        float wx = cb[m * 3], wy = cb[m * 3 + 1], wz = cb[m * 3 + 2];
        float p0 = __expf(d0 * 0.25f + alpha * (wx * c0x + wy * c0y + wz * c0z));
        float p1 = __expf(d1 * 0.25f + alpha * (wx * c1x + wy * c1y + wz * c1z));
        sm0 += p0; sm1 += p1;
        const float4* vr = (const float4*)(vb + (size_t)m * D_);
        float4 v0 = vr[0], v1 = vr[1], v2 = vr[2], v3 = vr[3];
        a0[0] += p0 * v0.x;  a0[1] += p0 * v0.y;  a0[2] += p0 * v0.z;  a0[3] += p0 * v0.w;
        a0[4] += p0 * v1.x;  a0[5] += p0 * v1.y;  a0[6] += p0 * v1.z;  a0[7] += p0 * v1.w;
        a0[8] += p0 * v2.x;  a0[9] += p0 * v2.y;  a0[10] += p0 * v2.z; a0[11] += p0 * v2.w;
        a0[12] += p0 * v3.x; a0[13] += p0 * v3.y; a0[14] += p0 * v3.z; a0[15] += p0 * v3.w;
        a1[0] += p1 * v0.x;  a1[1] += p1 * v0.y;  a1[2] += p1 * v0.z;  a1[3] += p1 * v0.w;
        a1[4] += p1 * v1.x;  a1[5] += p1 * v1.y;  a1[6] += p1 * v1.z;  a1[7] += p1 * v1.w;
        a1[8] += p1 * v2.x;  a1[9] += p1 * v2.y;  a1[10] += p1 * v2.z; a1[11] += p1 * v2.w;
        a1[12] += p1 * v3.x; a1[13] += p1 * v3.y; a1[14] += p1 * v3.z; a1[15] += p1 * v3.w;
    }
    // ---- two-round merge: a0 (queries 0..63) then a1 (queries 64..127) ----
    __shared__ float ssum[AW_][128];
    __shared__ float sacc[64][AW_ * DK_ + 1];    // 33KB, reused both rounds
    ssum[wid][lane] = sm0;      ssum[wid][lane + 64] = sm1;
    int qi = threadIdx.x & 63;                   // query within round
    int dq = threadIdx.x >> 6;                   // 0..7, 2 d's each
    // round 1
    #pragma unroll
    for (int d = 0; d < DK_; ++d) sacc[lane][wid * DK_ + d] = a0[d];
    __syncthreads();
    {
        int n = nb * 128 + qi;
        float* o = pp + (((size_t)bh * N_ + n) * KSP_ + ks) * PREC_;
        if (dq == 0) {
            float gsum = 0.f;
            #pragma unroll
            for (int w = 0; w < AW_; ++w) gsum += ssum[w][qi];
            o[0] = gsum;
        }
        #pragma unroll
        for (int dd = 0; dd < 2; ++dd) {
            int d = dq * 2 + dd;
            float a = 0.f;
            #pragma unroll
            for (int w = 0; w < AW_; ++w) a += sacc[qi][w * DK_ + d];
            o[1 + d] = a;
        }
    }
    __syncthreads();
    // round 2
    #pragma unroll
    for (int d = 0; d < DK_; ++d) sacc[lane][wid * DK_ + d] = a1[d];
    __syncthreads();
    {
        int n = nb * 128 + 64 + qi;
        float* o = pp + (((size_t)bh * N_ + n) * KSP_ + ks) * PREC_;
        if (dq == 0) {
            float gsum = 0.f;
            #pragma unroll
            for (int w = 0; w < AW_; ++w) gsum += ssum[w][qi + 64];
            o[0] = gsum;
        }
        #pragma unroll
        for (int dd = 0; dd < 2; ++dd) {
            int d = dq * 2 + dd;
            float a = 0.f;
            #pragma unroll
            for (int w = 0; w < AW_; ++w) a += sacc[qi][w * DK_ + d];
            o[1 + d] = a;
        }
    }
}

// ---------------- fused attn final-merge + residual + LayerNorm ------------
__global__ void attn_fin_ln(const float* __restrict__ pp,
                            const float* __restrict__ xin,
                            const float* __restrict__ g,
                            const float* __restrict__ bt,
                            float* __restrict__ xout) {
    int row = blockIdx.x * 4 + (threadIdx.x >> 6);   // b*N + n
    int lane = threadIdx.x & 63;
    int b = row >> 10, n = row & (N_ - 1);
    float v0, v1;
    {
        int c = lane;
        int h = c >> 4, d = c & 15;
        const float* p = pp + (((size_t)(b * 8 + h) * N_ + n) * KSP_) * PREC_;
        float gsum = 0.f, a = 0.f;
        #pragma unroll
        for (int s = 0; s < KSP_; ++s) {
            gsum += p[s * PREC_];
            a += p[s * PREC_ + 1 + d];
        }
        v0 = a / gsum + xin[(size_t)row * D_ + c];
    }
    {
        int c = lane + 64;
        int h = c >> 4, d = c & 15;
        const float* p = pp + (((size_t)(b * 8 + h) * N_ + n) * KSP_) * PREC_;
        float gsum = 0.f, a = 0.f;
        #pragma unroll
        for (int s = 0; s < KSP_; ++s) {
            gsum += p[s * PREC_];
            a += p[s * PREC_ + 1 + d];
        }
        v1 = a / gsum + xin[(size_t)row * D_ + c];
    }
    float mean = wave_sum(v0 + v1) * (1.0f / D_);
    float d0 = v0 - mean, d1 = v1 - mean;
    float var = wave_sum(d0 * d0 + d1 * d1) * (1.0f / D_);
    float rstd = rsqrtf(var + 1e-5f);
    float* orow = xout + (size_t)row * D_;
    orow[lane] = d0 * rstd * g[lane] + bt[lane];
    orow[lane + 64] = d1 * rstd * g[lane + 64] + bt[lane + 64];
}

// ---------------- column mean over N (global feature) ----------------------
__global__ void colmean_kernel(const float* __restrict__ x,
                               float* __restrict__ gc) {
    int b = blockIdx.x;
    int d = threadIdx.x & 127;
    int sl = threadIdx.x >> 7;
    __shared__ float part[4][128];
    float s = 0.f;
    const float* xb = x + (size_t)b * N_ * D_;
    for (int n = sl * 256; n < sl * 256 + 256; ++n) s += xb[(size_t)n * D_ + d];
    part[sl][d] = s;
    __syncthreads();
    if (sl == 0)
        gc[b * D_ + d] = (part[0][d] + part[1][d] + part[2][d] + part[3][d]) * (1.0f / N_);
}

// ---------------- child = pred + (h . cw + cb), interleaved x2 -------------
__global__ void child_kernel(const float* __restrict__ h,
                             const float* __restrict__ cw,
                             const float* __restrict__ cb,
                             const float* __restrict__ pred,
                             float* __restrict__ outp, int Nq) {
    int idx = blockIdx.x * blockDim.x + threadIdx.x;
    if (idx >= B_ * Nq * 6) return;
    int p = idx % 3;
    int t = (idx / 3) & 1;
    int n = (idx / 6) % Nq;
    int b = idx / (6 * Nq);
    const float* hr = h + ((size_t)b * Nq + n) * 256;
    float acc = cb[p];
    #pragma unroll 4
    for (int o = 0; o < 128; ++o) acc += hr[o * 2 + t] * cw[p * 128 + o];
    outp[idx] = pred[((size_t)b * Nq + n) * 3 + p] + acc;
}

// ---------------------------------------------------------------------------
static inline int cdiv(int a, int b) { return (a + b - 1) / b; }

extern "C" void kernel_launch(void* const* d_in, const int* in_sizes, int n_in,
                              void* d_out, int out_size, void* d_ws, size_t ws_size,
                              hipStream_t stream) {
    (void)in_sizes; (void)n_in; (void)out_size; (void)ws_size;
    const float* coords = (const float*)d_in[0];
    const float* gcn_w0 = (const float*)d_in[1];
    const float* gcn_b0 = (const float*)d_in[2];
    const float* gcn_w1 = (const float*)d_in[3];
    const float* gcn_b1 = (const float*)d_in[4];
    const float* enc_fw = (const float*)d_in[5];
    const float* enc_fb = (const float*)d_in[6];
    const float* t_wq   = (const float*)d_in[7];
    const float* t_bq   = (const float*)d_in[8];
    const float* t_wk   = (const float*)d_in[9];
    const float* t_bk   = (const float*)d_in[10];
    const float* t_wv   = (const float*)d_in[11];
    const float* t_bv   = (const float*)d_in[12];
    const float* t_alpha= (const float*)d_in[13];
    const float* t_f1w  = (const float*)d_in[14];
    const float* t_f1b  = (const float*)d_in[15];
    const float* t_f2w  = (const float*)d_in[16];
    const float* t_f2b  = (const float*)d_in[17];
    const float* t_ln1g = (const float*)d_in[18];
    const float* t_ln1b = (const float*)d_in[19];
    const float* t_ln2g = (const float*)d_in[20];
    const float* t_ln2b = (const float*)d_in[21];
    const float* dec_w1 = (const float*)d_in[22];
    const float* dec_b1 = (const float*)d_in[23];
    const float* dec_w2 = (const float*)d_in[24];
    const float* dec_b2 = (const float*)d_in[25];
    const float* st_sw1 = (const float*)d_in[26];
    const float* st_sb1 = (const float*)d_in[27];
    const float* st_sw2 = (const float*)d_in[28];
    const float* st_sb2 = (const float*)d_in[29];
    const float* st_dw  = (const float*)d_in[30];
    const float* st_db  = (const float*)d_in[31];
    const float* st_cw  = (const float*)d_in[32];
    const float* st_cb  = (const float*)d_in[33];
    float* out = (float*)d_out;

    // ---- workspace carve ----
    char* ws = (char*)d_ws;
    size_t off = 0;
    auto alloc = [&](size_t bytes) -> void* {
        void* p = ws + off;
        off += (bytes + 255) & ~(size_t)255;
        return p;
    };
    int*   knn   = (int*)  alloc((size_t)B_ * N_ * KG_ * 4);
    float* ppd   = (float*)alloc((size_t)B_ * 2048 * NCH_ * KG_ * 4);
    int*   ppi   = (int*)  alloc((size_t)B_ * 2048 * NCH_ * KG_ * 4);
    float* app   = (float*)alloc((size_t)B_ * H_ * N_ * KSP_ * PREC_ * 4);
    float* agg   = (float*)alloc((size_t)B_ * N_ * 64 * 4);
    float* x64   = (float*)alloc((size_t)B_ * N_ * 64 * 4);
    float* xb    = (float*)alloc((size_t)B_ * N_ * D_ * 4);
    float* x     = (float*)alloc((size_t)B_ * N_ * D_ * 4);
    float* q     = (float*)alloc((size_t)B_ * N_ * D_ * 4);
    float* k     = (float*)alloc((size_t)B_ * N_ * D_ * 4);
    float* v     = (float*)alloc((size_t)B_ * N_ * D_ * 4);
    float* ffh   = (float*)alloc((size_t)B_ * N_ * 512 * 4);
    float* gc    = (float*)alloc((size_t)B_ * D_ * 4);
    float* dech  = (float*)alloc((size_t)B_ * D_ * 4);
    float* pts0  = (float*)alloc((size_t)B_ * COARSE_ * 3 * 4);
    float* pts1  = (float*)alloc((size_t)B_ * 1024 * 3 * 4);
    float* pts2  = (float*)alloc((size_t)B_ * 2048 * 3 * 4);
    float* comb  = (float*)alloc((size_t)B_ * 2048 * 6 * 4);
    float* seedh = (float*)alloc((size_t)B_ * 2048 * 128 * 4);
    float* seed  = (float*)alloc((size_t)B_ * 2048 * 128 * 4);
    float* hb    = (float*)alloc((size_t)B_ * 2048 * 256 * 4);

    const int rows = B_ * N_;   // 2048

    // ---- graph encoder ----
    knn_part_kernel<<<B_ * NCH_ * 16, 64, 0, stream>>>(coords, ppd, ppi);
    knn_merge_kernel<<<B_ * N_ / MQ_, 256, 0, stream>>>(ppd, ppi, knn);
    gcn_agg_kernel<<<cdiv(rows * 3, 256), 256, 0, stream>>>(coords, knn, agg, 3);
    linear4_kernel<true><<<cdiv(rows * 16, 256), 256, 0, stream>>>(agg, gcn_w0, gcn_b0, x64, rows, 3, 64);
    gcn_agg_kernel<<<cdiv(rows * 64, 256), 256, 0, stream>>>(x64, knn, agg, 64);
    gemm128_kernel<64, true, false><<<dim3(rows / 8, 1), 256, 0, stream>>>(agg, gcn_w1, gcn_b1, xb, 128, 128);
    gemm128_kernel<128, false, false><<<dim3(rows / 8, 1), 256, 0, stream>>>(xb, enc_fw, enc_fb, x, 128, 128);

    // ---- transformer ----
    for (int i = 0; i < L_; ++i) {
        qkv3_kernel<<<dim3(rows / 8, 3), 256, 0, stream>>>(
            x, t_wq + i * 16384, t_bq + i * 128, t_wk + i * 16384, t_bk + i * 128,
            t_wv + i * 16384, t_bv + i * 128, q, k, v);
        attn_part<<<B_ * H_ * (N_ / 128) * KSP_, 512, 0, stream>>>(q, k, v, coords, t_alpha, i, app);
        attn_fin_ln<<<rows / 4, 256, 0, stream>>>(app, x, t_ln1g + i * 128, t_ln1b + i * 128, x);
        gemm128_kernel<128, true, false><<<dim3(rows / 8, 4), 256, 0, stream>>>(x, t_f1w + i * 128 * 512, t_f1b + i * 512, ffh, 512, 512);
        gemm_ln_kernel<512><<<rows / 8, 256, 0, stream>>>(ffh, t_f2w + i * 512 * 128, t_f2b + i * 128, x, t_ln2g + i * 128, t_ln2b + i * 128, x);
    }

    // ---- decoder coarse ----
    colmean_kernel<<<B_, 512, 0, stream>>>(x, gc);
    linear4_kernel<true><<<cdiv(B_ * 32, 256), 256, 0, stream>>>(gc, dec_w1, dec_b1, dech, B_, 128, 128);
    linear4_kernel<false><<<cdiv(B_ * 384, 256), 256, 0, stream>>>(dech, dec_w2, dec_b2, pts0, B_, 128, 1536);

    // ---- refine stages ----
    const float* pred = pts0;
    float* outs[3] = { pts1, pts2, out };
    int Nq = COARSE_;
    for (int s = 0; s < 3; ++s) {
        loc_part_kernel<<<dim3(Nq / 64, NCH_, B_), 64, 0, stream>>>(coords, pred, ppd, ppi, Nq);
        loc_merge_kernel<<<(B_ * Nq) / MQ_, 256, 0, stream>>>(coords, pred, ppd, ppi, comb, Nq);
        int srows = B_ * Nq;
        linear4_kernel<true><<<cdiv(srows * 32, 256), 256, 0, stream>>>(comb, st_sw1 + s * 6 * 128, st_sb1 + s * 128, seedh, srows, 6, 128);
        gemm128_kernel<128, false, false><<<dim3(srows / 8, 1), 256, 0, stream>>>(seedh, st_sw2 + s * 128 * 128, st_sb2 + s * 128, seed, 128, 128);
        gemm128_kernel<128, true, true><<<dim3(srows / 8, 2), 256, 0, stream>>>(seed, st_dw + s * 128 * 256, st_db + s * 128, hb, 256, 256);
        child_kernel<<<cdiv(srows * 6, 256), 256, 0, stream>>>(hb, st_cw + s * 3 * 128, st_cb + s * 3, pred, outs[s], Nq);
        pred = outs[s];
        Nq <<= 1;
    }
}

// Round 12
// 595.111 us; speedup vs baseline: 2.7020x; 2.7020x over previous
//
#include <hip/hip_runtime.h>

// ---------------------------------------------------------------------------
// FullModelSnowflake.  R11: revert R10's __launch_bounds__(512,7) — it forced
// VGPR 68->36 by spilling the 32-reg accumulators to scratch (1.34GB/dispatch
// HBM traffic, 54->300us).  Keep the two-round LDS merge (37KB, conflict-free
// reduce indexing).
// ---------------------------------------------------------------------------

#define B_ 2
#define N_ 1024
#define D_ 128
#define H_ 8
#define DK_ 16
#define L_ 4
#define KG_ 16
#define KLOC_ 8
#define COARSE_ 512
#define NCH_ 16          // candidate chunks (64 candidates each)
#define AW_ 8            // waves per attention block
#define KSP_ 4           // block-level key splits
#define PREC_ 17         // floats per attention partial (sum + 16 acc)
#define MQ_ 16           // queries per merge block

static __device__ __forceinline__ float wave_sum(float v) {
    #pragma unroll
    for (int off = 32; off > 0; off >>= 1) v += __shfl_xor(v, off);
    return v;
}
static __device__ __forceinline__ float half_sum(float v) {
    #pragma unroll
    for (int off = 16; off > 0; off >>= 1) v += __shfl_xor(v, off);
    return v;
}

// ---------------- LDS-staged GEMM body: returns this thread's acc ----------
template <int CIN, bool RELU, bool BIAS_HALF>
static __device__ __forceinline__ float4 gemm_body(
        const float* __restrict__ X, const float* __restrict__ W,
        const float* __restrict__ bias, int wstride, int col0) {
    __shared__ float Xs[8 * CIN];
    __shared__ float Ws[64][128];
    int tid = threadIdx.x;
    int row0 = blockIdx.x * 8;
    constexpr int NX4 = 2 * CIN;
    {
        const float4* xg = (const float4*)(X + (size_t)row0 * CIN);
        float4* xs4 = (float4*)Xs;
        #pragma unroll
        for (int i = 0; i < (NX4 + 255) / 256; ++i) {
            int t = tid + i * 256;
            if ((NX4 % 256 == 0) || t < NX4) xs4[t] = xg[t];
        }
    }
    int col4 = (tid & 31) << 2;
    int rowl = tid >> 5;
    float4 acc;
    if (BIAS_HALF) {
        acc.x = bias[(col0 + col4) >> 1];
        acc.y = bias[(col0 + col4 + 1) >> 1];
        acc.z = bias[(col0 + col4 + 2) >> 1];
        acc.w = bias[(col0 + col4 + 3) >> 1];
    } else {
        acc = *(const float4*)(bias + col0 + col4);
    }
    for (int c0 = 0; c0 < CIN; c0 += 64) {
        __syncthreads();
        #pragma unroll
        for (int i = 0; i < 8; ++i) {
            int flat = tid + i * 256;
            int wr = flat >> 5, wc = (flat & 31) << 2;
            *(float4*)&Ws[wr][wc] =
                *(const float4*)(W + (size_t)(c0 + wr) * wstride + col0 + wc);
        }
        __syncthreads();
        const float* xrow = Xs + rowl * CIN + c0;
        #pragma unroll
        for (int c = 0; c < 64; ++c) {
            float xv = xrow[c];
            float4 w = *(const float4*)&Ws[c][col4];
            acc.x += xv * w.x; acc.y += xv * w.y;
            acc.z += xv * w.z; acc.w += xv * w.w;
        }
    }
    if (RELU) {
        acc.x = fmaxf(acc.x, 0.f); acc.y = fmaxf(acc.y, 0.f);
        acc.z = fmaxf(acc.z, 0.f); acc.w = fmaxf(acc.w, 0.f);
    }
    return acc;
}

template <int CIN, bool RELU, bool BIAS_HALF>
__global__ __launch_bounds__(256) void gemm128_kernel(
        const float* __restrict__ X, const float* __restrict__ W,
        const float* __restrict__ bias, float* __restrict__ Y,
        int wstride, int ystride) {
    int col0 = blockIdx.y * 128;
    float4 acc = gemm_body<CIN, RELU, BIAS_HALF>(X, W, bias, wstride, col0);
    int col4 = (threadIdx.x & 31) << 2;
    int row = blockIdx.x * 8 + (threadIdx.x >> 5);
    *(float4*)(Y + (size_t)row * ystride + col0 + col4) = acc;
}

// GEMM (Cout=128) fused with residual-add + LayerNorm epilogue.
template <int CIN>
__global__ __launch_bounds__(256) void gemm_ln_kernel(
        const float* __restrict__ X, const float* __restrict__ W,
        const float* __restrict__ bias, const float* __restrict__ res,
        const float* __restrict__ g, const float* __restrict__ bt,
        float* __restrict__ Y) {
    float4 acc = gemm_body<CIN, false, false>(X, W, bias, 128, 0);
    int col4 = (threadIdx.x & 31) << 2;
    int row = blockIdx.x * 8 + (threadIdx.x >> 5);
    float4 r = *(const float4*)(res + (size_t)row * D_ + col4);
    acc.x += r.x; acc.y += r.y; acc.z += r.z; acc.w += r.w;
    float mean = half_sum(acc.x + acc.y + acc.z + acc.w) * (1.0f / D_);
    float dx = acc.x - mean, dy = acc.y - mean, dz = acc.z - mean, dw = acc.w - mean;
    float var = half_sum(dx * dx + dy * dy + dz * dz + dw * dw) * (1.0f / D_);
    float rstd = rsqrtf(var + 1e-5f);
    float4 gv = *(const float4*)(g + col4);
    float4 bv = *(const float4*)(bt + col4);
    float4 o;
    o.x = dx * rstd * gv.x + bv.x;
    o.y = dy * rstd * gv.y + bv.y;
    o.z = dz * rstd * gv.z + bv.z;
    o.w = dw * rstd * gv.w + bv.w;
    *(float4*)(Y + (size_t)row * D_ + col4) = o;
}

// fused QKV: 3 W-panels via blockIdx.y
__global__ __launch_bounds__(256) void qkv3_kernel(
        const float* __restrict__ X,
        const float* __restrict__ Wq, const float* __restrict__ bq,
        const float* __restrict__ Wk, const float* __restrict__ bk,
        const float* __restrict__ Wv, const float* __restrict__ bv,
        float* __restrict__ Q, float* __restrict__ K, float* __restrict__ V) {
    const float* W; const float* bias; float* Y;
    if (blockIdx.y == 0)      { W = Wq; bias = bq; Y = Q; }
    else if (blockIdx.y == 1) { W = Wk; bias = bk; Y = K; }
    else                      { W = Wv; bias = bv; Y = V; }
    float4 acc = gemm_body<128, false, false>(X, W, bias, 128, 0);
    int col4 = (threadIdx.x & 31) << 2;
    int row = blockIdx.x * 8 + (threadIdx.x >> 5);
    *(float4*)(Y + (size_t)row * 128 + col4) = acc;
}

// ---------------- KNN pass 1: per-chunk partial top-16 ---------------------
__global__ void knn_part_kernel(const float* __restrict__ coords,
                                float* __restrict__ pd, int* __restrict__ pi) {
    int blk = blockIdx.x;
    int qb = blk & 15;
    int ch = (blk >> 4) & 15;
    int b = blk >> 8;
    int lane = threadIdx.x;
    int q = qb * 64 + lane;
    __shared__ float4 sc[64];
    const float* cb = coords + (size_t)b * N_ * 3;
    {
        int m = ch * 64 + lane;
        float x = cb[m * 3], y = cb[m * 3 + 1], z = cb[m * 3 + 2];
        sc[lane] = make_float4(x, y, z, x * x + y * y + z * z);
    }
    __syncthreads();
    float qx = cb[q * 3], qy = cb[q * 3 + 1], qz = cb[q * 3 + 2];
    float q2 = qx * qx + qy * qy + qz * qz;
    float bd[KG_]; int bi[KG_];
    #pragma unroll
    for (int j = 0; j < KG_; ++j) { bd[j] = 3e38f; bi[j] = 0; }
    for (int j = 0; j < 64; ++j) {
        int m = ch * 64 + j;
        float4 c = sc[j];
        float dot = qx * c.x + qy * c.y + qz * c.z;
        float d = (q2 - 2.0f * dot) + c.w;
        d = (m == q) ? 3e38f : d;
        if (d < bd[KG_ - 1]) {
            #pragma unroll
            for (int jj = KG_ - 1; jj > 0; --jj) {
                bool shf = d < bd[jj - 1];
                bool plc = !shf && (d < bd[jj]);
                bd[jj] = shf ? bd[jj - 1] : (plc ? d : bd[jj]);
                bi[jj] = shf ? bi[jj - 1] : (plc ? m : bi[jj]);
            }
            if (d < bd[0]) { bd[0] = d; bi[0] = m; }
        }
    }
    size_t base = (((size_t)b * N_ + q) * NCH_ + ch) * KG_;
    #pragma unroll
    for (int j = 0; j < KG_; ++j) { pd[base + j] = bd[j]; pi[base + j] = bi[j]; }
}

// ---------------- KNN pass 2: LDS-staged merge of 16 sorted lists ----------
__global__ __launch_bounds__(256) void knn_merge_kernel(
        const float* __restrict__ pd, const int* __restrict__ pi,
        int* __restrict__ knn) {
    __shared__ float sd[MQ_][NCH_ * KG_ + 1];
    __shared__ int   si[MQ_][NCH_ * KG_ + 1];
    size_t qg0 = (size_t)blockIdx.x * MQ_;
    size_t base = qg0 * NCH_ * KG_;
    for (int i = threadIdx.x; i < MQ_ * NCH_ * KG_; i += 256) {
        int r = i >> 8, cix = i & 255;
        sd[r][cix] = pd[base + i];
        si[r][cix] = pi[base + i];
    }
    __syncthreads();
    int t = threadIdx.x;
    if (t < MQ_) {
        const float* cd0 = sd[t];
        const int* ci0 = si[t];
        float bd[KG_]; int bi[KG_];
        #pragma unroll
        for (int j = 0; j < KG_; ++j) { bd[j] = 3e38f; bi[j] = 0; }
        for (int ch = 0; ch < NCH_; ++ch) {
            for (int e = 0; e < KG_; ++e) {
                float d = cd0[ch * KG_ + e];
                if (d >= bd[KG_ - 1]) break;
                int m = ci0[ch * KG_ + e];
                #pragma unroll
                for (int jj = KG_ - 1; jj > 0; --jj) {
                    bool shf = d < bd[jj - 1];
                    bool plc = !shf && (d < bd[jj]);
                    bd[jj] = shf ? bd[jj - 1] : (plc ? d : bd[jj]);
                    bi[jj] = shf ? bi[jj - 1] : (plc ? m : bi[jj]);
                }
                if (d < bd[0]) { bd[0] = d; bi[0] = m; }
            }
        }
        int* o = knn + (qg0 + t) * KG_;
        #pragma unroll
        for (int j = 0; j < KG_; ++j) o[j] = bi[j];
    }
}

// ---------------- local KNN pass 1 (k=8) -----------------------------------
__global__ void loc_part_kernel(const float* __restrict__ part,
                                const float* __restrict__ pred,
                                float* __restrict__ pd, int* __restrict__ pi,
                                int Nq) {
    int qb = blockIdx.x, ch = blockIdx.y, b = blockIdx.z;
    int lane = threadIdx.x;
    int q = qb * 64 + lane;
    __shared__ float4 sc[64];
    const float* pb = part + (size_t)b * N_ * 3;
    {
        int m = ch * 64 + lane;
        float x = pb[m * 3], y = pb[m * 3 + 1], z = pb[m * 3 + 2];
        sc[lane] = make_float4(x, y, z, x * x + y * y + z * z);
    }
    __syncthreads();
    const float* pr = pred + ((size_t)b * Nq + q) * 3;
    float qx = pr[0], qy = pr[1], qz = pr[2];
    float q2 = qx * qx + qy * qy + qz * qz;
    float bd[KLOC_]; int bi[KLOC_];
    #pragma unroll
    for (int j = 0; j < KLOC_; ++j) { bd[j] = 3e38f; bi[j] = 0; }
    for (int j = 0; j < 64; ++j) {
        float4 c = sc[j];
        float dot = qx * c.x + qy * c.y + qz * c.z;
        float d = (q2 - 2.0f * dot) + c.w;
        if (d < bd[KLOC_ - 1]) {
            int m = ch * 64 + j;
            #pragma unroll
            for (int jj = KLOC_ - 1; jj > 0; --jj) {
                bool shf = d < bd[jj - 1];
                bool plc = !shf && (d < bd[jj]);
                bd[jj] = shf ? bd[jj - 1] : (plc ? d : bd[jj]);
                bi[jj] = shf ? bi[jj - 1] : (plc ? m : bi[jj]);
            }
            if (d < bd[0]) { bd[0] = d; bi[0] = m; }
        }
    }
    size_t base = (((size_t)b * Nq + q) * NCH_ + ch) * KLOC_;
    #pragma unroll
    for (int j = 0; j < KLOC_; ++j) { pd[base + j] = bd[j]; pi[base + j] = bi[j]; }
}

// ---------------- local KNN pass 2: LDS-staged merge + mean + comb ---------
__global__ __launch_bounds__(256) void loc_merge_kernel(
        const float* __restrict__ part, const float* __restrict__ pred,
        const float* __restrict__ pd, const int* __restrict__ pi,
        float* __restrict__ comb, int Nq) {
    __shared__ float sd[MQ_][NCH_ * KLOC_ + 1];
    __shared__ int   si[MQ_][NCH_ * KLOC_ + 1];
    size_t qg0 = (size_t)blockIdx.x * MQ_;
    size_t base = qg0 * NCH_ * KLOC_;
    for (int i = threadIdx.x; i < MQ_ * NCH_ * KLOC_; i += 256) {
        int r = i >> 7, cix = i & 127;
        sd[r][cix] = pd[base + i];
        si[r][cix] = pi[base + i];
    }
    __syncthreads();
    int t = threadIdx.x;
    if (t < MQ_) {
        const float* cd0 = sd[t];
        const int* ci0 = si[t];
        float bd[KLOC_]; int bi[KLOC_];
        #pragma unroll
        for (int j = 0; j < KLOC_; ++j) { bd[j] = 3e38f; bi[j] = 0; }
        for (int ch = 0; ch < NCH_; ++ch) {
            for (int e = 0; e < KLOC_; ++e) {
                float d = cd0[ch * KLOC_ + e];
                if (d >= bd[KLOC_ - 1]) break;
                int m = ci0[ch * KLOC_ + e];
                #pragma unroll
                for (int jj = KLOC_ - 1; jj > 0; --jj) {
                    bool shf = d < bd[jj - 1];
                    bool plc = !shf && (d < bd[jj]);
                    bd[jj] = shf ? bd[jj - 1] : (plc ? d : bd[jj]);
                    bi[jj] = shf ? bi[jj - 1] : (plc ? m : bi[jj]);
                }
                if (d < bd[0]) { bd[0] = d; bi[0] = m; }
            }
        }
        size_t qg = qg0 + t;
        int b = (int)(qg / Nq);
        const float* pb = part + (size_t)b * N_ * 3;
        float sx = 0.f, sy = 0.f, sz = 0.f;
        #pragma unroll
        for (int j = 0; j < KLOC_; ++j) {
            int m = bi[j];
            sx += pb[m * 3]; sy += pb[m * 3 + 1]; sz += pb[m * 3 + 2];
        }
        const float* pr = pred + qg * 3;
        float* o = comb + qg * 6;
        o[0] = pr[0]; o[1] = pr[1]; o[2] = pr[2];
        o[3] = sx * (1.0f / KLOC_); o[4] = sy * (1.0f / KLOC_); o[5] = sz * (1.0f / KLOC_);
    }
}

// ---------------- GCN aggregation: (x + sum_nb) / (k+1) --------------------
__global__ void gcn_agg_kernel(const float* __restrict__ x,
                               const int* __restrict__ knn,
                               float* __restrict__ agg, int C) {
    int i = blockIdx.x * blockDim.x + threadIdx.x;
    if (i >= B_ * N_ * C) return;
    int c = i % C;
    int n = (i / C) % N_;
    int b = i / (C * N_);
    const int* id = knn + ((size_t)b * N_ + n) * KG_;
    float s = x[((size_t)b * N_ + n) * C + c];
    #pragma unroll
    for (int j = 0; j < KG_; ++j) s += x[((size_t)b * N_ + id[j]) * C + c];
    agg[i] = s * (1.0f / (KG_ + 1));
}

// ---------------- linear: 4 outputs per thread (small cases) ---------------
template <bool RELU>
__global__ void linear4_kernel(const float* __restrict__ X,
                               const float* __restrict__ W,
                               const float* __restrict__ bias,
                               float* __restrict__ Y,
                               int rows, int Cin, int Cout) {
    int co4 = Cout >> 2;
    int idx = blockIdx.x * blockDim.x + threadIdx.x;
    if (idx >= rows * co4) return;
    int r = idx / co4, o4 = (idx - r * co4) << 2;
    const float* x = X + (size_t)r * Cin;
    float4 acc = *(const float4*)(bias + o4);
    #pragma unroll 4
    for (int c = 0; c < Cin; ++c) {
        float xv = x[c];
        float4 w = *(const float4*)(W + (size_t)c * Cout + o4);
        acc.x += xv * w.x; acc.y += xv * w.y; acc.z += xv * w.z; acc.w += xv * w.w;
    }
    if (RELU) {
        acc.x = fmaxf(acc.x, 0.f); acc.y = fmaxf(acc.y, 0.f);
        acc.z = fmaxf(acc.z, 0.f); acc.w = fmaxf(acc.w, 0.f);
    }
    *(float4*)(Y + (size_t)r * Cout + o4) = acc;
}

// ---------------- attention: no-max softmax, two-round LDS merge -----------
__global__ __launch_bounds__(512) void attn_part(
        const float* __restrict__ q,
        const float* __restrict__ k,
        const float* __restrict__ v,
        const float* __restrict__ coords,
        const float* __restrict__ alphap, int layer,
        float* __restrict__ pp) {
    int bh = blockIdx.x & 15;          // b*8 + h
    int t = blockIdx.x >> 4;           // nb*KSP + ks
    int ks = t & (KSP_ - 1);
    int nb = t >> 2;
    int h = bh & 7;
    int b = bh >> 3;
    int wid = threadIdx.x >> 6;
    int lane = threadIdx.x & 63;
    int n0 = nb * 128 + lane;          // second query: n0 + 64
    float alpha = alphap[layer];
    const float* qp0 = q + ((size_t)(b * N_ + n0) * D_ + h * DK_);
    const float* qp1 = qp0 + (size_t)64 * D_;
    float qv0[DK_], qv1[DK_];
    #pragma unroll
    for (int d = 0; d < DK_; ++d) { qv0[d] = qp0[d]; qv1[d] = qp1[d]; }
    const float* cb = coords + (size_t)b * N_ * 3;
    float c0x = cb[n0 * 3], c0y = cb[n0 * 3 + 1], c0z = cb[n0 * 3 + 2];
    float c1x = cb[(n0 + 64) * 3], c1y = cb[(n0 + 64) * 3 + 1], c1z = cb[(n0 + 64) * 3 + 2];
    const float* kb = k + (size_t)b * N_ * D_ + h * DK_;
    const float* vb = v + (size_t)b * N_ * D_ + h * DK_;
    float sm0 = 0.f, sm1 = 0.f;
    float a0[DK_], a1[DK_];
    #pragma unroll
    for (int d = 0; d < DK_; ++d) { a0[d] = 0.f; a1[d] = 0.f; }
    int kbase = ks * 256 + wid * 32;
    #pragma unroll 4
    for (int j = 0; j < 32; ++j) {
        int m = kbase + j;
        const float4* kr = (const float4*)(kb + (size_t)m * D_);
        float4 k0 = kr[0], k1 = kr[1], k2 = kr[2], k3 = kr[3];
        float d0 = qv0[0] * k0.x + qv0[1] * k0.y + qv0[2] * k0.z + qv0[3] * k0.w
                 + qv0[4] * k1.x + qv0[5] * k1.y + qv0[6] * k1.z + qv0[7] * k1.w
                 + qv0[8] * k2.x + qv0[9] * k2.y + qv0[10] * k2.z + qv0[11] * k2.w
                 + qv0[12] * k3.x + qv0[13] * k3.y + qv0[14] * k3.z + qv0[15] * k3.w;
        float d1 = qv1[0] * k0.x + qv1[1] * k0.y + qv1[2] * k0.z + qv1[3] * k0.w
                 + qv1[4] * k1.x + qv1[5] * k1.y + qv1[6] * k1.z + qv1[7] * k1.w
                 + qv1[8] * k2.x + qv1[9] * k2.y + qv1[10] * k2.z + qv1[11] * k2.w
                 + qv1[12] * k3.x + qv1[13] * k3.y + qv1[14] * k3.z + qv1[15] * k3.w;
        float wx = cb[m * 3], wy = cb[m * 3 + 1], wz = cb[m * 3 + 2];
        float p0 = __expf(d0 * 0.25f + alpha * (wx * c0x + wy * c0y + wz * c0z));
        float p1 = __expf(d1 * 0.25f + alpha * (wx * c1x + wy * c1y + wz * c1z));
        sm0 += p0; sm1 += p1;
        const float4* vr = (const float4*)(vb + (size_t)m * D_);
        float4 v0 = vr[0], v1 = vr[1], v2 = vr[2], v3 = vr[3];
        a0[0] += p0 * v0.x;  a0[1] += p0 * v0.y;  a0[2] += p0 * v0.z;  a0[3] += p0 * v0.w;
        a0[4] += p0 * v1.x;  a0[5] += p0 * v1.y;  a0[6] += p0 * v1.z;  a0[7] += p0 * v1.w;
        a0[8] += p0 * v2.x;  a0[9] += p0 * v2.y;  a0[10] += p0 * v2.z; a0[11] += p0 * v2.w;
        a0[12] += p0 * v3.x; a0[13] += p0 * v3.y; a0[14] += p0 * v3.z; a0[15] += p0 * v3.w;
        a1[0] += p1 * v0.x;  a1[1] += p1 * v0.y;  a1[2] += p1 * v0.z;  a1[3] += p1 * v0.w;
        a1[4] += p1 * v1.x;  a1[5] += p1 * v1.y;  a1[6] += p1 * v1.z;  a1[7] += p1 * v1.w;
        a1[8] += p1 * v2.x;  a1[9] += p1 * v2.y;  a1[10] += p1 * v2.z; a1[11] += p1 * v2.w;
        a1[12] += p1 * v3.x; a1[13] += p1 * v3.y; a1[14] += p1 * v3.z; a1[15] += p1 * v3.w;
    }
    // ---- two-round merge: a0 (queries 0..63) then a1 (queries 64..127) ----
    __shared__ float ssum[AW_][128];
    __shared__ float sacc[64][AW_ * DK_ + 1];    // 33KB, reused both rounds
    ssum[wid][lane] = sm0;      ssum[wid][lane + 64] = sm1;
    int qi = threadIdx.x & 63;                   // query within round
    int dq = threadIdx.x >> 6;                   // 0..7, 2 d's each
    // round 1
    #pragma unroll
    for (int d = 0; d < DK_; ++d) sacc[lane][wid * DK_ + d] = a0[d];
    __syncthreads();
    {
        int n = nb * 128 + qi;
        float* o = pp + (((size_t)bh * N_ + n) * KSP_ + ks) * PREC_;
        if (dq == 0) {
            float gsum = 0.f;
            #pragma unroll
            for (int w = 0; w < AW_; ++w) gsum += ssum[w][qi];
            o[0] = gsum;
        }
        #pragma unroll
        for (int dd = 0; dd < 2; ++dd) {
            int d = dq * 2 + dd;
            float a = 0.f;
            #pragma unroll
            for (int w = 0; w < AW_; ++w) a += sacc[qi][w * DK_ + d];
            o[1 + d] = a;
        }
    }
    __syncthreads();
    // round 2
    #pragma unroll
    for (int d = 0; d < DK_; ++d) sacc[lane][wid * DK_ + d] = a1[d];
    __syncthreads();
    {
        int n = nb * 128 + 64 + qi;
        float* o = pp + (((size_t)bh * N_ + n) * KSP_ + ks) * PREC_;
        if (dq == 0) {
            float gsum = 0.f;
            #pragma unroll
            for (int w = 0; w < AW_; ++w) gsum += ssum[w][qi + 64];
            o[0] = gsum;
        }
        #pragma unroll
        for (int dd = 0; dd < 2; ++dd) {
            int d = dq * 2 + dd;
            float a = 0.f;
            #pragma unroll
            for (int w = 0; w < AW_; ++w) a += sacc[qi][w * DK_ + d];
            o[1 + d] = a;
        }
    }
}

// ---------------- fused attn final-merge + residual + LayerNorm ------------
__global__ void attn_fin_ln(const float* __restrict__ pp,
                            const float* __restrict__ xin,
                            const float* __restrict__ g,
                            const float* __restrict__ bt,
                            float* __restrict__ xout) {
    int row = blockIdx.x * 4 + (threadIdx.x >> 6);   // b*N + n
    int lane = threadIdx.x & 63;
    int b = row >> 10, n = row & (N_ - 1);
    float v0, v1;
    {
        int c = lane;
        int h = c >> 4, d = c & 15;
        const float* p = pp + (((size_t)(b * 8 + h) * N_ + n) * KSP_) * PREC_;
        float gsum = 0.f, a = 0.f;
        #pragma unroll
        for (int s = 0; s < KSP_; ++s) {
            gsum += p[s * PREC_];
            a += p[s * PREC_ + 1 + d];
        }
        v0 = a / gsum + xin[(size_t)row * D_ + c];
    }
    {
        int c = lane + 64;
        int h = c >> 4, d = c & 15;
        const float* p = pp + (((size_t)(b * 8 + h) * N_ + n) * KSP_) * PREC_;
        float gsum = 0.f, a = 0.f;
        #pragma unroll
        for (int s = 0; s < KSP_; ++s) {
            gsum += p[s * PREC_];
            a += p[s * PREC_ + 1 + d];
        }
        v1 = a / gsum + xin[(size_t)row * D_ + c];
    }
    float mean = wave_sum(v0 + v1) * (1.0f / D_);
    float d0 = v0 - mean, d1 = v1 - mean;
    float var = wave_sum(d0 * d0 + d1 * d1) * (1.0f / D_);
    float rstd = rsqrtf(var + 1e-5f);
    float* orow = xout + (size_t)row * D_;
    orow[lane] = d0 * rstd * g[lane] + bt[lane];
    orow[lane + 64] = d1 * rstd * g[lane + 64] + bt[lane + 64];
}

// ---------------- column mean over N (global feature) ----------------------
__global__ void colmean_kernel(const float* __restrict__ x,
                               float* __restrict__ gc) {
    int b = blockIdx.x;
    int d = threadIdx.x & 127;
    int sl = threadIdx.x >> 7;
    __shared__ float part[4][128];
    float s = 0.f;
    const float* xb = x + (size_t)b * N_ * D_;
    for (int n = sl * 256; n < sl * 256 + 256; ++n) s += xb[(size_t)n * D_ + d];
    part[sl][d] = s;
    __syncthreads();
    if (sl == 0)
        gc[b * D_ + d] = (part[0][d] + part[1][d] + part[2][d] + part[3][d]) * (1.0f / N_);
}

// ---------------- child = pred + (h . cw + cb), interleaved x2 -------------
__global__ void child_kernel(const float* __restrict__ h,
                             const float* __restrict__ cw,
                             const float* __restrict__ cb,
                             const float* __restrict__ pred,
                             float* __restrict__ outp, int Nq) {
    int idx = blockIdx.x * blockDim.x + threadIdx.x;
    if (idx >= B_ * Nq * 6) return;
    int p = idx % 3;
    int t = (idx / 3) & 1;
    int n = (idx / 6) % Nq;
    int b = idx / (6 * Nq);
    const float* hr = h + ((size_t)b * Nq + n) * 256;
    float acc = cb[p];
    #pragma unroll 4
    for (int o = 0; o < 128; ++o) acc += hr[o * 2 + t] * cw[p * 128 + o];
    outp[idx] = pred[((size_t)b * Nq + n) * 3 + p] + acc;
}

// ---------------------------------------------------------------------------
static inline int cdiv(int a, int b) { return (a + b - 1) / b; }

extern "C" void kernel_launch(void* const* d_in, const int* in_sizes, int n_in,
                              void* d_out, int out_size, void* d_ws, size_t ws_size,
                              hipStream_t stream) {
    (void)in_sizes; (void)n_in; (void)out_size; (void)ws_size;
    const float* coords = (const float*)d_in[0];
    const float* gcn_w0 = (const float*)d_in[1];
    const float* gcn_b0 = (const float*)d_in[2];
    const float* gcn_w1 = (const float*)d_in[3];
    const float* gcn_b1 = (const float*)d_in[4];
    const float* enc_fw = (const float*)d_in[5];
    const float* enc_fb = (const float*)d_in[6];
    const float* t_wq   = (const float*)d_in[7];
    const float* t_bq   = (const float*)d_in[8];
    const float* t_wk   = (const float*)d_in[9];
    const float* t_bk   = (const float*)d_in[10];
    const float* t_wv   = (const float*)d_in[11];
    const float* t_bv   = (const float*)d_in[12];
    const float* t_alpha= (const float*)d_in[13];
    const float* t_f1w  = (const float*)d_in[14];
    const float* t_f1b  = (const float*)d_in[15];
    const float* t_f2w  = (const float*)d_in[16];
    const float* t_f2b  = (const float*)d_in[17];
    const float* t_ln1g = (const float*)d_in[18];
    const float* t_ln1b = (const float*)d_in[19];
    const float* t_ln2g = (const float*)d_in[20];
    const float* t_ln2b = (const float*)d_in[21];
    const float* dec_w1 = (const float*)d_in[22];
    const float* dec_b1 = (const float*)d_in[23];
    const float* dec_w2 = (const float*)d_in[24];
    const float* dec_b2 = (const float*)d_in[25];
    const float* st_sw1 = (const float*)d_in[26];
    const float* st_sb1 = (const float*)d_in[27];
    const float* st_sw2 = (const float*)d_in[28];
    const float* st_sb2 = (const float*)d_in[29];
    const float* st_dw  = (const float*)d_in[30];
    const float* st_db  = (const float*)d_in[31];
    const float* st_cw  = (const float*)d_in[32];
    const float* st_cb  = (const float*)d_in[33];
    float* out = (float*)d_out;

    // ---- workspace carve ----
    char* ws = (char*)d_ws;
    size_t off = 0;
    auto alloc = [&](size_t bytes) -> void* {
        void* p = ws + off;
        off += (bytes + 255) & ~(size_t)255;
        return p;
    };
    int*   knn   = (int*)  alloc((size_t)B_ * N_ * KG_ * 4);
    float* ppd   = (float*)alloc((size_t)B_ * 2048 * NCH_ * KG_ * 4);
    int*   ppi   = (int*)  alloc((size_t)B_ * 2048 * NCH_ * KG_ * 4);
    float* app   = (float*)alloc((size_t)B_ * H_ * N_ * KSP_ * PREC_ * 4);
    float* agg   = (float*)alloc((size_t)B_ * N_ * 64 * 4);
    float* x64   = (float*)alloc((size_t)B_ * N_ * 64 * 4);
    float* xb    = (float*)alloc((size_t)B_ * N_ * D_ * 4);
    float* x     = (float*)alloc((size_t)B_ * N_ * D_ * 4);
    float* q     = (float*)alloc((size_t)B_ * N_ * D_ * 4);
    float* k     = (float*)alloc((size_t)B_ * N_ * D_ * 4);
    float* v     = (float*)alloc((size_t)B_ * N_ * D_ * 4);
    float* ffh   = (float*)alloc((size_t)B_ * N_ * 512 * 4);
    float* gc    = (float*)alloc((size_t)B_ * D_ * 4);
    float* dech  = (float*)alloc((size_t)B_ * D_ * 4);
    float* pts0  = (float*)alloc((size_t)B_ * COARSE_ * 3 * 4);
    float* pts1  = (float*)alloc((size_t)B_ * 1024 * 3 * 4);
    float* pts2  = (float*)alloc((size_t)B_ * 2048 * 3 * 4);
    float* comb  = (float*)alloc((size_t)B_ * 2048 * 6 * 4);
    float* seedh = (float*)alloc((size_t)B_ * 2048 * 128 * 4);
    float* seed  = (float*)alloc((size_t)B_ * 2048 * 128 * 4);
    float* hb    = (float*)alloc((size_t)B_ * 2048 * 256 * 4);

    const int rows = B_ * N_;   // 2048

    // ---- graph encoder ----
    knn_part_kernel<<<B_ * NCH_ * 16, 64, 0, stream>>>(coords, ppd, ppi);
    knn_merge_kernel<<<B_ * N_ / MQ_, 256, 0, stream>>>(ppd, ppi, knn);
    gcn_agg_kernel<<<cdiv(rows * 3, 256), 256, 0, stream>>>(coords, knn, agg, 3);
    linear4_kernel<true><<<cdiv(rows * 16, 256), 256, 0, stream>>>(agg, gcn_w0, gcn_b0, x64, rows, 3, 64);
    gcn_agg_kernel<<<cdiv(rows * 64, 256), 256, 0, stream>>>(x64, knn, agg, 64);
    gemm128_kernel<64, true, false><<<dim3(rows / 8, 1), 256, 0, stream>>>(agg, gcn_w1, gcn_b1, xb, 128, 128);
    gemm128_kernel<128, false, false><<<dim3(rows / 8, 1), 256, 0, stream>>>(xb, enc_fw, enc_fb, x, 128, 128);

    // ---- transformer ----
    for (int i = 0; i < L_; ++i) {
        qkv3_kernel<<<dim3(rows / 8, 3), 256, 0, stream>>>(
            x, t_wq + i * 16384, t_bq + i * 128, t_wk + i * 16384, t_bk + i * 128,
            t_wv + i * 16384, t_bv + i * 128, q, k, v);
        attn_part<<<B_ * H_ * (N_ / 128) * KSP_, 512, 0, stream>>>(q, k, v, coords, t_alpha, i, app);
        attn_fin_ln<<<rows / 4, 256, 0, stream>>>(app, x, t_ln1g + i * 128, t_ln1b + i * 128, x);
        gemm128_kernel<128, true, false><<<dim3(rows / 8, 4), 256, 0, stream>>>(x, t_f1w + i * 128 * 512, t_f1b + i * 512, ffh, 512, 512);
        gemm_ln_kernel<512><<<rows / 8, 256, 0, stream>>>(ffh, t_f2w + i * 512 * 128, t_f2b + i * 128, x, t_ln2g + i * 128, t_ln2b + i * 128, x);
    }

    // ---- decoder coarse ----
    colmean_kernel<<<B_, 512, 0, stream>>>(x, gc);
    linear4_kernel<true><<<cdiv(B_ * 32, 256), 256, 0, stream>>>(gc, dec_w1, dec_b1, dech, B_, 128, 128);
    linear4_kernel<false><<<cdiv(B_ * 384, 256), 256, 0, stream>>>(dech, dec_w2, dec_b2, pts0, B_, 128, 1536);

    // ---- refine stages ----
    const float* pred = pts0;
    float* outs[3] = { pts1, pts2, out };
    int Nq = COARSE_;
    for (int s = 0; s < 3; ++s) {
        loc_part_kernel<<<dim3(Nq / 64, NCH_, B_), 64, 0, stream>>>(coords, pred, ppd, ppi, Nq);
        loc_merge_kernel<<<(B_ * Nq) / MQ_, 256, 0, stream>>>(coords, pred, ppd, ppi, comb, Nq);
        int srows = B_ * Nq;
        linear4_kernel<true><<<cdiv(srows * 32, 256), 256, 0, stream>>>(comb, st_sw1 + s * 6 * 128, st_sb1 + s * 128, seedh, srows, 6, 128);
        gemm128_kernel<128, false, false><<<dim3(srows / 8, 1), 256, 0, stream>>>(seedh, st_sw2 + s * 128 * 128, st_sb2 + s * 128, seed, 128, 128);
        gemm128_kernel<128, true, true><<<dim3(srows / 8, 2), 256, 0, stream>>>(seed, st_dw + s * 128 * 256, st_db + s * 128, hb, 256, 256);
        child_kernel<<<cdiv(srows * 6, 256), 256, 0, stream>>>(hb, st_cw + s * 3 * 128, st_cb + s * 3, pred, outs[s], Nq);
        pred = outs[s];
        Nq <<= 1;
    }
}